// Round 20
// baseline (3047.626 us; speedup 1.0000x reference)
//
#include <hip/hip_runtime.h>

typedef unsigned int uint;
typedef unsigned short ushort;
typedef _Float16 f16;
typedef _Float16 f16x2 __attribute__((ext_vector_type(2)));
typedef _Float16 f16x8 __attribute__((ext_vector_type(8)));
typedef float f32x4 __attribute__((ext_vector_type(4)));

#define N_TYPES 10000
#define HID 256
#define G4 1024
#define BATCH 32
#define SEQ 1024
#define KTR 7    // K-tiles (of 32) held in registers; tile 7 lives in LDS

// ---------------- K1: path table: path[n][h] = sum_d cumw_d * emb[anc[n,d]][h]
__global__ void k_path(const int* __restrict__ anc, const float* __restrict__ weight,
                       const float* __restrict__ emb, int D, f16* __restrict__ path) {
  int n = blockIdx.x;
  int h = threadIdx.x;
  float acc = 0.f, cw = 1.f;
  for (int d = 0; d < D; ++d) {
    int a = anc[n * D + d];
    if (a < 0) break;
    acc += cw * emb[a * HID + h];
    cw *= weight[a];
  }
  path[n * HID + h] = (f16)acc;
}

// ---------------- K0: convert W_ih -> f16, W_hh -> transposed packed f16 pairs, bias = b_ih+b_hh
// whh_t layout: [128 kpair][1024 row] u32 (pair = f16 k, k+1 of row)
__global__ void k_conv(const float* __restrict__ wih, const float* __restrict__ whh,
                       const float* __restrict__ bih, const float* __restrict__ bhh,
                       f16* __restrict__ wih_h, uint* __restrict__ whh_t,
                       float* __restrict__ bias) {
  int i = blockIdx.x * 256 + threadIdx.x;   // 262144 threads
  wih_h[i] = (f16)wih[i];
  if (i < G4 * 128) {
    int row = i >> 7, p = i & 127;
    f16x2 v;
    v.x = (f16)whh[row * HID + 2 * p];
    v.y = (f16)whh[row * HID + 2 * p + 1];
    whh_t[p * G4 + row] = __builtin_bit_cast(uint, v);
  }
  if (i < G4) bias[i] = bih[i] + bhh[i];
}

// ---------------- K2: proj[n][dim][gate] = path[n]@W_ih^T + b (gate-packed epilogue)
#define BM 128
#define BN 128
#define BK 64
#define LPAD 72
__global__ __launch_bounds__(256) void k_gemm(const f16* __restrict__ A,
                                              const f16* __restrict__ Bw,
                                              const float* __restrict__ bias,
                                              f16* __restrict__ C) {
  __shared__ f16 sA[BM][LPAD];
  __shared__ f16 sB[BN][LPAD];
  int m0 = blockIdx.x * BM, n0 = blockIdx.y * BN;
  int tid = threadIdx.x;
  int wid = tid >> 6, lane = tid & 63;
  int wm = wid & 1, wn = wid >> 1;
  f32x4 acc[4][4] = {};
  for (int k0 = 0; k0 < 256; k0 += BK) {
    __syncthreads();
    int r = tid >> 3, kc = (tid & 7) * 8;
    for (int i = 0; i < 4; ++i) {
      int row = r + 32 * i;
      int gm = m0 + row;
      uint4 va = make_uint4(0u, 0u, 0u, 0u);
      if (gm < N_TYPES) va = *(const uint4*)&A[gm * 256 + k0 + kc];
      *(uint4*)&sA[row][kc] = va;
      uint4 vb = *(const uint4*)&Bw[(n0 + row) * 256 + k0 + kc];
      *(uint4*)&sB[row][kc] = vb;
    }
    __syncthreads();
#pragma unroll
    for (int ks = 0; ks < 2; ++ks) {
      f16x8 af[4], bf[4];
      int kk = ks * 32 + (lane >> 4) * 8;
#pragma unroll
      for (int mt = 0; mt < 4; ++mt)
        af[mt] = *(const f16x8*)&sA[wm * 64 + mt * 16 + (lane & 15)][kk];
#pragma unroll
      for (int nt = 0; nt < 4; ++nt)
        bf[nt] = *(const f16x8*)&sB[wn * 64 + nt * 16 + (lane & 15)][kk];
#pragma unroll
      for (int mt = 0; mt < 4; ++mt)
#pragma unroll
        for (int nt = 0; nt < 4; ++nt)
          acc[mt][nt] = __builtin_amdgcn_mfma_f32_16x16x32_f16(af[mt], bf[nt], acc[mt][nt], 0, 0, 0);
    }
  }
#pragma unroll
  for (int mt = 0; mt < 4; ++mt)
#pragma unroll
    for (int nt = 0; nt < 4; ++nt)
#pragma unroll
      for (int qq = 0; qq < 4; ++qq) {
        int row = m0 + wm * 64 + mt * 16 + (lane >> 4) * 4 + qq;
        int col = n0 + wn * 64 + nt * 16 + (lane & 15);
        int dim = col & 255, g = col >> 8;
        if (row < N_TYPES)
          C[row * G4 + dim * 4 + g] = (f16)(acc[mt][nt][qq] + bias[col]);
      }
}

// ---------------- K3: LSTM recurrence, v20 = single-CU + MFMA matvec.
// R19 post-mortem: single-CU is VALU-issue-bound (~77% per-active-CU VALUBusy;
// 584 VALU ops/thread/step incl. accvgpr reads). Fix: matrix cores. Per wave,
// 8 Mt x 8 Kt mfma_f32_16x16x32_f16 cover its 128 rows x K=256: 640cy/SIMD vs
// ~2300cy VALU. h is BROADCAST into all 16 B-columns (all C-cols equal; we read
// rows from lanes l&15==0) -- no zero-padding needed, B-frag load is a clean LDS
// broadcast. Weights pre-formatted ONCE into A-fragment layout (k_gemm's proven
// operand pattern): 7 Kt in registers (wa[8][7]=224 regs; R19 proved 328/thread
// works), Kt=7 in LDS (64KB, per-lane b128, conflict-free). C-extract: lanes
// l&15==0 hold 4 contiguous rows/tile -> one ds_write_b128 per Mt into sl.
// All sync = __syncthreads on ONE CU (no cross-CU fabric -- the R5-R17 RTT
// plateau does not apply).
__device__ __forceinline__ float sigm(float v) { return 1.f / (1.f + __expf(-v)); }
__device__ __forceinline__ float tanh_(float v) { return 1.f - 2.f / (__expf(2.f * v) + 1.f); }
__device__ __forceinline__ float f16u(ushort u) { return (float)__builtin_bit_cast(f16, u); }

__global__ __launch_bounds__(512)
__attribute__((amdgpu_waves_per_eu(2, 2)))
void k_lstm(const int* __restrict__ evs,
            const f16* __restrict__ proj,
            const uint* __restrict__ whh_t,
            float* __restrict__ out) {
  int b = blockIdx.x;                  // one batch per WG per CU
  int t = threadIdx.x;
  int w = t >> 6, l = t & 63;
  int lm = l & 15, lk = l >> 4;        // m-within-tile, k-group

  __shared__ uint4 wtail[8][8][64];    // A-frags for Kt=KTR: [wave][mt][lane], 64KB
  __shared__ float sl[1024];           // per-row matvec sums
  __shared__ uint hl[128];             // h packed f16 pairs

  // ---- one-time: A-fragments. Fragment (w,mt,kt): lane l holds
  // Whh[w*128+mt*16+lm][kt*32+lk*8+jj], jj=0..7 -> 4 u32 pairs p=kt*16+lk*4+j.
  uint4 wa[8][KTR];
#pragma unroll
  for (int mt = 0; mt < 8; ++mt) {
    int row = w * 128 + mt * 16 + lm;
#pragma unroll
    for (int kt = 0; kt < KTR; ++kt) {
      int p = kt * 16 + lk * 4;
      uint4 a;
      a.x = whh_t[(p + 0) * G4 + row];
      a.y = whh_t[(p + 1) * G4 + row];
      a.z = whh_t[(p + 2) * G4 + row];
      a.w = whh_t[(p + 3) * G4 + row];
      wa[mt][kt] = a;
    }
    {
      int p = KTR * 16 + lk * 4;
      uint4 a;
      a.x = whh_t[(p + 0) * G4 + row];
      a.y = whh_t[(p + 1) * G4 + row];
      a.z = whh_t[(p + 2) * G4 + row];
      a.w = whh_t[(p + 3) * G4 + row];
      wtail[w][mt][l] = a;
    }
  }

  const int* ev = evs + b * SEQ;
  float c = 0.f, hval_prev = 0.f;

  __syncthreads();                     // staging visible

  for (int step = 0; step < SEQ; ++step) {
    // ---- phase 0: ALL per-step vmem (prev out store + x gather); retires under MFMA
    float x0 = 0.f, x1 = 0.f, x2 = 0.f, x3 = 0.f;
    if (t < 256) {
      if (step > 0) out[((step - 1) * BATCH + b) * HID + t] = hval_prev;
      ushort4 xv = *(const ushort4*)(proj + (long)ev[step] * G4 + t * 4);
      x0 = f16u(xv.x); x1 = f16u(xv.y); x2 = f16u(xv.z); x3 = f16u(xv.w);
    }

    // ---- phase 1: MFMA matvec (rows w*128..w*128+127, K=256)
    f32x4 acc[8] = {};                 // fresh accumulation each step
    if (step > 0) {
      uint4 hb[8];
#pragma unroll
      for (int kt = 0; kt < 8; ++kt)   // broadcast h: addr depends on lk only
        hb[kt] = *(const uint4*)&hl[kt * 16 + lk * 4];
#pragma unroll
      for (int kt = 0; kt < KTR; ++kt)
#pragma unroll
        for (int mt = 0; mt < 8; ++mt)
          acc[mt] = __builtin_amdgcn_mfma_f32_16x16x32_f16(
              __builtin_bit_cast(f16x8, wa[mt][kt]),
              __builtin_bit_cast(f16x8, hb[kt]), acc[mt], 0, 0, 0);
#pragma unroll
      for (int mt = 0; mt < 8; ++mt) { // LDS tail Kt=KTR (per-lane b128, no conflict)
        uint4 a = wtail[w][mt][l];
        acc[mt] = __builtin_amdgcn_mfma_f32_16x16x32_f16(
            __builtin_bit_cast(f16x8, a),
            __builtin_bit_cast(f16x8, hb[KTR]), acc[mt], 0, 0, 0);
      }
    }
    // C-extract: col 0 rows live in lanes lm==0: D[row=mt*16+lk*4+reg][0] = acc[mt][reg]
    if (lm == 0) {
#pragma unroll
      for (int mt = 0; mt < 8; ++mt)
        *(f32x4*)&sl[w * 128 + mt * 16 + lk * 4] = acc[mt];
    }
    __syncthreads();                   // [A] all row sums visible

    // ---- phase 2: finale on t<256 (dim t): gates + c/h + pack h to LDS
    if (t < 256) {
      float s0 = sl[t]       + x0;     // gate i
      float s1 = sl[256 + t] + x1;     // gate f
      float s2 = sl[512 + t] + x2;     // gate g
      float s3 = sl[768 + t] + x3;     // gate o
      float iv = sigm(s0), fv = sigm(s1), gv = tanh_(s2), ov = sigm(s3);
      c = fv * c + iv * gv;
      float hval = ov * tanh_(c);
      hval_prev = hval;                // out store deferred to phase 0 next step
      float hn = __shfl_down(hval, 1);
      if ((t & 1) == 0) {
        f16x2 pk; pk.x = (f16)hval; pk.y = (f16)hn;
        hl[t >> 1] = __builtin_bit_cast(uint, pk);
      }
    }
    __syncthreads();                   // [B] h visible for next step's B-frags
    // hazards (intra-WG, barrier-ordered): sl written phase1(s) pre-A, read
    // phase2(s) A..B, rewritten phase1(s+1) post-B. hl read phase1(s) pre-A,
    // written phase2(s) A..B. All safe.
  }
  if (t < 256) out[((SEQ - 1) * BATCH + b) * HID + t] = hval_prev;
}

extern "C" void kernel_launch(void* const* d_in, const int* in_sizes, int n_in,
                              void* d_out, int out_size, void* d_ws, size_t ws_size,
                              hipStream_t stream) {
  (void)n_in; (void)out_size; (void)ws_size;
  const int* evs = (const int*)d_in[0];
  const int* anc = (const int*)d_in[1];
  const float* weight = (const float*)d_in[2];
  const float* emb = (const float*)d_in[3];
  const float* wih = (const float*)d_in[4];
  const float* whh = (const float*)d_in[5];
  const float* bih = (const float*)d_in[6];
  const float* bhh = (const float*)d_in[7];
  int D = in_sizes[1] / N_TYPES;

  char* ws = (char*)d_ws;
  f16* path = (f16*)(ws);                       // 10000*256*2 = 5,120,000 (dead after k_gemm)
  f16* wih_h = (f16*)(ws + 5242880);            // 524,288
  uint* whh_t = (uint*)(ws + 5767168);          // 524,288
  float* bias = (float*)(ws + 6291456);         // 4,096
  f16* proj = (f16*)(ws + 6295552);             // 10000*1024*2 = 20,480,000 (gate-packed)
  float* out = (float*)d_out;

  k_conv<<<1024, 256, 0, stream>>>(wih, whh, bih, bhh, wih_h, whh_t, bias);
  k_path<<<N_TYPES, 256, 0, stream>>>(anc, weight, emb, D, path);
  k_gemm<<<dim3(79, 8), 256, 0, stream>>>(path, wih_h, bias, proj);
  k_lstm<<<32, 512, 0, stream>>>(evs, proj, whh_t, out);   // one WG per batch
}